// Round 9
// baseline (7494.906 us; speedup 1.0000x reference)
//
#include <hip/hip_runtime.h>
#include <cstdint>
#include <cstddef>

// ---------- types ----------
typedef _Float16 half2v __attribute__((ext_vector_type(2)));
typedef _Float16 half4v __attribute__((ext_vector_type(4)));
typedef _Float16 half8v __attribute__((ext_vector_type(8)));
typedef float f32x4 __attribute__((ext_vector_type(4)));

#if __has_builtin(__builtin_amdgcn_fdot2)
#define FDOT2(a, b, c) __builtin_amdgcn_fdot2((a), (b), (c), false)
#else
static __device__ __forceinline__ float fdot2_fb(half2v a, half2v b, float c) {
    return c + (float)a[0] * (float)b[0] + (float)a[1] * (float)b[1];
}
#define FDOT2(a, b, c) fdot2_fb((a), (b), (c))
#endif

#define SV2(v, i0, i1) __builtin_shufflevector((v), (v), (i0), (i1))

__device__ __forceinline__ float sigm(float x) { return 1.0f / (1.0f + __expf(-x)); }
__device__ __forceinline__ float tanh_(float x) { return 1.0f - 2.0f / (__expf(2.0f * x) + 1.0f); }

// Problem constants
#define BB 128
#define TT 512
#define II 300
#define IIP 320   // padded K for fp16 path
#define HH 256
#define GG 1024  // 4*H

// ============================================================================
// Kernel 0: convert X (65536x300 f32) and W_ih_f (1024x300 f32) to fp16 with
// zero-padded K=320 rows, enabling 16B-aligned global_load_lds in the GEMM.
// ============================================================================
__global__ __launch_bounds__(256) void cvt_xw(
    const float* __restrict__ X, const float* __restrict__ W,
    _Float16* __restrict__ Xh, _Float16* __restrict__ Wh)
{
    const int total = (65536 + 1024) * 40;   // 8-elem chunks per padded row
    for (int c = blockIdx.x * 256 + threadIdx.x; c < total; c += gridDim.x * 256) {
        const int row = c / 40;
        const int ch = c - row * 40;
        const int k0 = ch * 8;
        const float* src;
        _Float16* dst;
        if (row < 65536) {
            src = X + (size_t)row * II;
            dst = Xh + (size_t)row * IIP;
        } else {
            src = W + (size_t)(row - 65536) * II;
            dst = Wh + (size_t)(row - 65536) * IIP;
        }
        half8v hv;
        if (k0 + 8 <= II) {
            float4 a = *(const float4*)(src + k0);
            float4 b = *(const float4*)(src + k0 + 4);
            hv = half8v{(_Float16)a.x, (_Float16)a.y, (_Float16)a.z, (_Float16)a.w,
                        (_Float16)b.x, (_Float16)b.y, (_Float16)b.z, (_Float16)b.w};
        } else {
#pragma unroll
            for (int q = 0; q < 8; ++q) {
                const int k = k0 + q;
                hv[q] = (k < II) ? (_Float16)src[k] : (_Float16)0.f;
            }
        }
        *(half8v*)(dst + k0) = hv;
    }
}

// ============================================================================
// Kernel 1b: xp GEMM, fp16 inputs via global_load_lds (m97 structure). PROVEN.
// ============================================================================
#if __has_builtin(__builtin_amdgcn_global_load_lds)
#define HAVE_GLL 1
__device__ __forceinline__ void gll16(const _Float16* g, _Float16* l) {
    __builtin_amdgcn_global_load_lds(
        (const __attribute__((address_space(1))) void*)g,
        (__attribute__((address_space(3))) void*)l, 16, 0, 0);
}
#else
#define HAVE_GLL 0
#endif

__global__ __launch_bounds__(256) void gemm_xp_h(
    const _Float16* __restrict__ Xh, const _Float16* __restrict__ Wh,
    const float* __restrict__ bias, _Float16* __restrict__ XP)
{
    __shared__ __align__(16) _Float16 As[128 * 32];
    __shared__ __align__(16) _Float16 Bs[128 * 32];

    const int t = threadIdx.x;
    const int m0 = blockIdx.y * 128;
    const int n0 = blockIdx.x * 128;
    const int lane = t & 63;
    const int wv = t >> 6;
    const int mq = (wv >> 1) * 4;
    const int nq = (wv & 1) * 4;

    int rowd[2], k4d[2], cidx[2];
#pragma unroll
    for (int r = 0; r < 2; ++r) {
        const int c = wv * 128 + r * 64 + lane;
        cidx[r] = c;
        rowd[r] = ((c >> 6) << 4) | (c & 15);
        k4d[r] = (c >> 4) & 3;
    }

    f32x4 acc[4][4];
#pragma unroll
    for (int i = 0; i < 4; ++i)
#pragma unroll
        for (int j = 0; j < 4; ++j) acc[i][j] = f32x4{0.f, 0.f, 0.f, 0.f};

    for (int kc = 0; kc < IIP; kc += 32) {
        __syncthreads();
#pragma unroll
        for (int r = 0; r < 2; ++r) {
            const _Float16* ga = Xh + (size_t)(m0 + rowd[r]) * IIP + kc + k4d[r] * 8;
            const _Float16* gb = Wh + (size_t)(n0 + rowd[r]) * IIP + kc + k4d[r] * 8;
#if HAVE_GLL
            gll16(ga, &As[cidx[r] * 8]);
            gll16(gb, &Bs[cidx[r] * 8]);
#else
            *(half8v*)(&As[cidx[r] * 8]) = *(const half8v*)ga;
            *(half8v*)(&Bs[cidx[r] * 8]) = *(const half8v*)gb;
#endif
        }
        __syncthreads();

        half8v af[4], bf[4];
#pragma unroll
        for (int i = 0; i < 4; ++i) {
            af[i] = *(const half8v*)(&As[(mq + i) * 512 + (lane >> 4) * 128 + (lane & 15) * 8]);
            bf[i] = *(const half8v*)(&Bs[(nq + i) * 512 + (lane >> 4) * 128 + (lane & 15) * 8]);
        }
#pragma unroll
        for (int i = 0; i < 4; ++i)
#pragma unroll
            for (int j = 0; j < 4; ++j)
                acc[i][j] = __builtin_amdgcn_mfma_f32_16x16x32_f16(af[i], bf[j], acc[i][j], 0, 0, 0);
    }

#pragma unroll
    for (int j = 0; j < 4; ++j) {
        const int n = n0 + (nq + j) * 16 + (lane & 15);
        const float bv = bias[n];
#pragma unroll
        for (int i = 0; i < 4; ++i) {
#pragma unroll
            for (int r = 0; r < 4; ++r) {
                const int m = m0 + (mq + i) * 16 + (lane >> 4) * 4 + r;
                XP[(size_t)m * GG + n] = (_Float16)(acc[i][j][r] + bv);
            }
        }
    }
}

// ============================================================================
// Kernel 1 (fallback): xp GEMM from f32 inputs (the proven v1 kernel).
// ============================================================================
__global__ __launch_bounds__(256, 3) void gemm_xp(
    const float* __restrict__ X, const float* __restrict__ W,
    const float* __restrict__ bias, _Float16* __restrict__ XP)
{
    __shared__ _Float16 As[128 * 32];
    __shared__ _Float16 Bs[128 * 32];

    const int t = threadIdx.x;
    const int m0 = blockIdx.y * 128;
    const int n0 = blockIdx.x * 128;
    const int kpos = t & 7;
    const int rbase = t >> 3;
    const int lane = t & 63;
    const int wv = t >> 6;
    const int mq = (wv >> 1) * 4;
    const int nq = (wv & 1) * 4;

    f32x4 acc[4][4];
#pragma unroll
    for (int i = 0; i < 4; ++i)
#pragma unroll
        for (int j = 0; j < 4; ++j) acc[i][j] = f32x4{0.f, 0.f, 0.f, 0.f};

    for (int kc = 0; kc < 320; kc += 32) {
        __syncthreads();
        const int k0 = kc + kpos * 4;
#pragma unroll
        for (int rr = 0; rr < 4; ++rr) {
            const int row = rbase + rr * 32;
            float4 va = {0.f, 0.f, 0.f, 0.f}, vb = {0.f, 0.f, 0.f, 0.f};
            if (k0 < 300) {
                va = *(const float4*)(X + (size_t)(m0 + row) * II + k0);
                vb = *(const float4*)(W + (size_t)(n0 + row) * II + k0);
            }
            const int idx = (row >> 4) * 512 + (kpos >> 1) * 128 + (row & 15) * 8 + (kpos & 1) * 4;
            half4v ha = {(_Float16)va.x, (_Float16)va.y, (_Float16)va.z, (_Float16)va.w};
            half4v hb = {(_Float16)vb.x, (_Float16)vb.y, (_Float16)vb.z, (_Float16)vb.w};
            *(half4v*)(&As[idx]) = ha;
            *(half4v*)(&Bs[idx]) = hb;
        }
        __syncthreads();

        half8v af[4], bf[4];
#pragma unroll
        for (int i = 0; i < 4; ++i) {
            af[i] = *(const half8v*)(&As[(mq + i) * 512 + (lane >> 4) * 128 + (lane & 15) * 8]);
            bf[i] = *(const half8v*)(&Bs[(nq + i) * 512 + (lane >> 4) * 128 + (lane & 15) * 8]);
        }
#pragma unroll
        for (int i = 0; i < 4; ++i)
#pragma unroll
            for (int j = 0; j < 4; ++j)
                acc[i][j] = __builtin_amdgcn_mfma_f32_16x16x32_f16(af[i], bf[j], acc[i][j], 0, 0, 0);
    }

#pragma unroll
    for (int j = 0; j < 4; ++j) {
        const int n = n0 + (nq + j) * 16 + (lane & 15);
        const float bv = bias[n];
#pragma unroll
        for (int i = 0; i < 4; ++i) {
#pragma unroll
            for (int r = 0; r < 4; ++r) {
                const int m = m0 + (mq + i) * 16 + (lane >> 4) * 4 + r;
                XP[(size_t)m * GG + n] = (_Float16)(acc[i][j][r] + bv);
            }
        }
    }
}

// ============================================================================
// Kernel 2 (v7b): v1 structure x TWO batch elements per block (64 blocks).
// (v7 with the SV2-in-loop compile error fixed by hand-unrolling.)
//
// v1 is latency-bound: VALU issue ~1600 cyc + LDS issue ~2560 cyc (h-reads
// are broadcasts) both < the 4617-cyc step; v2/v5 cut LDS work, no gain.
// v7 buys ILP: same resident weights, two independent accumulator pairs for
// batches b and b+64 -> 4 independent FDOT2 chains/thread fill the stalls;
// weight LDS reads amortize over 2 batches. Mapping, shfl_xor(32) exchange,
// 1 barrier/step, 192 VGPR ks + 64 LDS ks: v1 verbatim.
// ============================================================================
__global__ __attribute__((amdgpu_flat_work_group_size(512, 512), amdgpu_waves_per_eu(2, 2)))
void lstm_fwd(
    const float* __restrict__ Whh, const _Float16* __restrict__ XP,
    float* __restrict__ HF)
{
    __shared__ _Float16 wlds[8 * GG * 8];               // 128 KB: [grp][row][8]
    __shared__ __align__(16) _Float16 hlds[2][2][HH];   // 2 KB: [pp][batch][j]

    const int t = threadIdx.x;
    const int b0 = blockIdx.x;
    const int b1 = blockIdx.x + 64;
    const int l = t & 63;
    const int wv = t >> 6;
    const int half = l >> 5;               // 0: (i,g) rows, 1: (f,o) rows
    const int j = wv * 32 + (l & 31);      // gate index 0..255
    const int row0 = j + (half ? 256 : 0); // i_j or f_j
    const int row1 = row0 + 512;           // g_j or o_j

    // ---- resident weights: k = 0..191 for both owned rows (192 VGPRs) ----
    half2v w0[96], w1[96];
#pragma unroll
    for (int i = 0; i < 48; ++i) {
        float4 v = *(const float4*)(Whh + (size_t)row0 * HH + i * 4);
        w0[2 * i]     = half2v{(_Float16)v.x, (_Float16)v.y};
        w0[2 * i + 1] = half2v{(_Float16)v.z, (_Float16)v.w};
    }
#pragma unroll
    for (int i = 0; i < 48; ++i) {
        float4 v = *(const float4*)(Whh + (size_t)row1 * HH + i * 4);
        w1[2 * i]     = half2v{(_Float16)v.x, (_Float16)v.y};
        w1[2 * i + 1] = half2v{(_Float16)v.z, (_Float16)v.w};
    }
    // ---- LDS weights: k = 192..255, filled by row index t and t+512 ----
#pragma unroll
    for (int grp = 0; grp < 8; ++grp) {
        float4 a  = *(const float4*)(Whh + (size_t)t * HH + 192 + grp * 8);
        float4 c4 = *(const float4*)(Whh + (size_t)t * HH + 192 + grp * 8 + 4);
        half8v hv = {(_Float16)a.x, (_Float16)a.y, (_Float16)a.z, (_Float16)a.w,
                     (_Float16)c4.x, (_Float16)c4.y, (_Float16)c4.z, (_Float16)c4.w};
        *(half8v*)(&wlds[grp * (GG * 8) + t * 8]) = hv;
        float4 a2 = *(const float4*)(Whh + (size_t)(t + 512) * HH + 192 + grp * 8);
        float4 c2 = *(const float4*)(Whh + (size_t)(t + 512) * HH + 192 + grp * 8 + 4);
        half8v hv2 = {(_Float16)a2.x, (_Float16)a2.y, (_Float16)a2.z, (_Float16)a2.w,
                      (_Float16)c2.x, (_Float16)c2.y, (_Float16)c2.z, (_Float16)c2.w};
        *(half8v*)(&wlds[grp * (GG * 8) + (t + 512) * 8]) = hv2;
    }
    if (t < HH) { hlds[0][0][t] = (_Float16)0.f; hlds[0][1][t] = (_Float16)0.f; }
    float ca = 0.0f, cb = 0.0f;
    __syncthreads();

    const _Float16* xpa = XP + (size_t)b0 * TT * GG;
    const _Float16* xpb = XP + (size_t)b1 * TT * GG;
    _Float16 x0a = xpa[row0], x1a = xpa[row1];
    _Float16 x0b = xpb[row0], x1b = xpb[row1];

    for (int ts = 0; ts < TT; ++ts) {
        const int p = ts & 1;
        const _Float16* hra = &hlds[p][0][0];
        const _Float16* hrb = &hlds[p][1][0];
        // prefetch next step's xp (full step of latency to land)
        const size_t nstep = (ts < TT - 1) ? GG : 0;
        const _Float16 nx0a = xpa[nstep + row0], nx1a = xpa[nstep + row1];
        const _Float16 nx0b = xpb[nstep + row0], nx1b = xpb[nstep + row1];

        float a0a = 0.f, a1a = 0.f, a0b = 0.f, a1b = 0.f;
#pragma unroll
        for (int cq = 0; cq < 24; ++cq) {  // k = 0..191 from VGPR weights
            half8v hva = *(const half8v*)(&hra[cq * 8]);
            half8v hvb = *(const half8v*)(&hrb[cq * 8]);
            a0a = FDOT2(SV2(hva, 0, 1), w0[cq * 4 + 0], a0a);
            a1a = FDOT2(SV2(hva, 0, 1), w1[cq * 4 + 0], a1a);
            a0b = FDOT2(SV2(hvb, 0, 1), w0[cq * 4 + 0], a0b);
            a1b = FDOT2(SV2(hvb, 0, 1), w1[cq * 4 + 0], a1b);
            a0a = FDOT2(SV2(hva, 2, 3), w0[cq * 4 + 1], a0a);
            a1a = FDOT2(SV2(hva, 2, 3), w1[cq * 4 + 1], a1a);
            a0b = FDOT2(SV2(hvb, 2, 3), w0[cq * 4 + 1], a0b);
            a1b = FDOT2(SV2(hvb, 2, 3), w1[cq * 4 + 1], a1b);
            a0a = FDOT2(SV2(hva, 4, 5), w0[cq * 4 + 2], a0a);
            a1a = FDOT2(SV2(hva, 4, 5), w1[cq * 4 + 2], a1a);
            a0b = FDOT2(SV2(hvb, 4, 5), w0[cq * 4 + 2], a0b);
            a1b = FDOT2(SV2(hvb, 4, 5), w1[cq * 4 + 2], a1b);
            a0a = FDOT2(SV2(hva, 6, 7), w0[cq * 4 + 3], a0a);
            a1a = FDOT2(SV2(hva, 6, 7), w1[cq * 4 + 3], a1a);
            a0b = FDOT2(SV2(hvb, 6, 7), w0[cq * 4 + 3], a0b);
            a1b = FDOT2(SV2(hvb, 6, 7), w1[cq * 4 + 3], a1b);
        }
#define LDSW_Q(I0, I1)                                                  \
        {                                                               \
            half2v wap = SV2(wa, I0, I1);                               \
            half2v wbp = SV2(wb, I0, I1);                               \
            a0a = FDOT2(SV2(hva, I0, I1), wap, a0a);                    \
            a1a = FDOT2(SV2(hva, I0, I1), wbp, a1a);                    \
            a0b = FDOT2(SV2(hvb, I0, I1), wap, a0b);                    \
            a1b = FDOT2(SV2(hvb, I0, I1), wbp, a1b);                    \
        }
#pragma unroll
        for (int grp = 0; grp < 8; ++grp) {  // k = 192..255 from LDS weights
            half8v hva = *(const half8v*)(&hra[192 + grp * 8]);
            half8v hvb = *(const half8v*)(&hrb[192 + grp * 8]);
            half8v wa = *(const half8v*)(&wlds[grp * (GG * 8) + row0 * 8]);
            half8v wb = *(const half8v*)(&wlds[grp * (GG * 8) + row1 * 8]);
            LDSW_Q(0, 1)
            LDSW_Q(2, 3)
            LDSW_Q(4, 5)
            LDSW_Q(6, 7)
        }
#undef LDSW_Q

        // batch a: partner exchange + cell update
        {
            const float o0 = a0a + (float)x0a;
            const float o1 = a1a + (float)x1a;
            const float p0 = __shfl_xor(o0, 32, 64);
            const float p1 = __shfl_xor(o1, 32, 64);
            const float gi = half ? p0 : o0;
            const float gg = half ? p1 : o1;
            const float gf = half ? o0 : p0;
            const float go = half ? o1 : p1;
            ca = sigm(gf) * ca + sigm(gi) * tanh_(gg);
            const float h = sigm(go) * tanh_(ca);
            if (!half) {
                hlds[p ^ 1][0][j] = (_Float16)h;
                if (ts == TT - 1) HF[(size_t)b0 * HH + j] = h;
            }
        }
        // batch b: partner exchange + cell update
        {
            const float o0 = a0b + (float)x0b;
            const float o1 = a1b + (float)x1b;
            const float p0 = __shfl_xor(o0, 32, 64);
            const float p1 = __shfl_xor(o1, 32, 64);
            const float gi = half ? p0 : o0;
            const float gg = half ? p1 : o1;
            const float gf = half ? o0 : p0;
            const float go = half ? o1 : p1;
            cb = sigm(gf) * cb + sigm(gi) * tanh_(gg);
            const float h = sigm(go) * tanh_(cb);
            if (!half) {
                hlds[p ^ 1][1][j] = (_Float16)h;
                if (ts == TT - 1) HF[(size_t)b1 * HH + j] = h;
            }
        }
        __syncthreads();

        x0a = nx0a; x1a = nx1a; x0b = nx0b; x1b = nx1b;
        xpa += nstep; xpb += nstep;
    }
}

// ============================================================================
// Kernel 3: backward direction = ONE cell step on x[:, T-1] with h0=c0=0.
// ============================================================================
__global__ __launch_bounds__(256) void lstm_bwd(
    const float* __restrict__ X, const float* __restrict__ Wih,
    const float* __restrict__ bb, float* __restrict__ HB)
{
    __shared__ float xs[II];
    const int b = blockIdx.x, t = threadIdx.x;
    const float* xrow = X + ((size_t)b * TT + (TT - 1)) * II;
    if (t < 75) *(float4*)(&xs[t * 4]) = *(const float4*)(xrow + t * 4);
    __syncthreads();
    if (t < HH) {
        float ai = 0.f, ag = 0.f, ao = 0.f;
        const float4* wi = (const float4*)(Wih + (size_t)t * II);
        const float4* wg = (const float4*)(Wih + (size_t)(t + 512) * II);
        const float4* wo = (const float4*)(Wih + (size_t)(t + 768) * II);
        for (int k4 = 0; k4 < 75; ++k4) {
            float4 xv = *(const float4*)(&xs[k4 * 4]);
            float4 a = wi[k4], g4 = wg[k4], o4 = wo[k4];
            ai += xv.x * a.x + xv.y * a.y + xv.z * a.z + xv.w * a.w;
            ag += xv.x * g4.x + xv.y * g4.y + xv.z * g4.z + xv.w * g4.w;
            ao += xv.x * o4.x + xv.y * o4.y + xv.z * o4.z + xv.w * o4.w;
        }
        ai += bb[t];
        ag += bb[t + 512];
        ao += bb[t + 768];
        const float cg = sigm(ai) * tanh_(ag);
        HB[(size_t)b * HH + t] = sigm(ao) * tanh_(cg);
    }
}

// ============================================================================
// Kernel 4: out[b][jj] = [hf|hb] . W_lin[jj] + b_lin[jj]
// ============================================================================
__global__ __launch_bounds__(256) void final_k(
    const float* __restrict__ HF, const float* __restrict__ HB,
    const float* __restrict__ Wlin, const float* __restrict__ blin,
    float* __restrict__ OUT)
{
    const int t = threadIdx.x;
    const int b = t >> 1, jj = t & 1;
    float acc = blin[jj];
    const float* wf = Wlin + jj * 512;
    const float* wb = Wlin + jj * 512 + 256;
    const float* hf = HF + (size_t)b * HH;
    const float* hb = HB + (size_t)b * HH;
    for (int k = 0; k < HH; k += 4) {
        float4 h4 = *(const float4*)(hf + k);
        float4 w4 = *(const float4*)(wf + k);
        float4 g4 = *(const float4*)(hb + k);
        float4 v4 = *(const float4*)(wb + k);
        acc += h4.x * w4.x + h4.y * w4.y + h4.z * w4.z + h4.w * w4.w;
        acc += g4.x * v4.x + g4.y * v4.y + g4.z * v4.z + g4.w * v4.w;
    }
    OUT[b * 2 + jj] = acc;
}

// ============================================================================
extern "C" void kernel_launch(void* const* d_in, const int* in_sizes, int n_in,
                              void* d_out, int out_size, void* d_ws, size_t ws_size,
                              hipStream_t stream)
{
    const float* x = (const float*)d_in[0];
    const float* Wihf = (const float*)d_in[1];
    const float* Whhf = (const float*)d_in[2];
    const float* bf = (const float*)d_in[3];
    const float* Wihb = (const float*)d_in[4];
    const float* Whhb = (const float*)d_in[5];
    const float* bbv = (const float*)d_in[6];
    const float* Wlin = (const float*)d_in[7];
    const float* blin = (const float*)d_in[8];
    float* out = (float*)d_out;
    (void)Whhb; (void)in_sizes; (void)n_in; (void)out_size;

    // workspace layout: xp fp16 | hf f32 | hb f32 | Xh fp16 | Wh fp16
    const size_t XP_B = (size_t)BB * TT * GG * 2;            // 134,217,728
    const size_t H_B  = (size_t)BB * HH * 4;                 // 131,072
    const size_t XH_B = (size_t)65536 * IIP * 2;             // 41,943,040
    const size_t WH_B = (size_t)GG * IIP * 2;                // 655,360

    _Float16* xp = (_Float16*)d_ws;
    float* hf = (float*)((char*)d_ws + XP_B);
    float* hb = hf + (size_t)BB * HH;
    _Float16* Xh = (_Float16*)((char*)d_ws + XP_B + 2 * H_B);
    _Float16* Wh = Xh + (size_t)65536 * IIP;

    lstm_bwd<<<BB, 256, 0, stream>>>(x, Wihb, bbv, hb);
    if (ws_size >= XP_B + 2 * H_B + XH_B + WH_B) {
        cvt_xw<<<2048, 256, 0, stream>>>(x, Wihf, Xh, Wh);
        gemm_xp_h<<<dim3(GG / 128, (BB * TT) / 128), 256, 0, stream>>>(Xh, Wh, bf, xp);
    } else {
        gemm_xp<<<dim3(GG / 128, (BB * TT) / 128), 256, 0, stream>>>(x, Wihf, bf, xp);
    }
    lstm_fwd<<<BB / 2, 512, 0, stream>>>(Whhf, xp, hf);
    final_k<<<1, 256, 0, stream>>>(hf, hb, Wlin, blin, out);
}

// Round 10
// 1264.152 us; speedup vs baseline: 5.9288x; 5.9288x over previous
//
#include <hip/hip_runtime.h>
#include <cstdint>
#include <cstddef>

// ---------- types ----------
typedef _Float16 half2v __attribute__((ext_vector_type(2)));
typedef _Float16 half4v __attribute__((ext_vector_type(4)));
typedef _Float16 half8v __attribute__((ext_vector_type(8)));
typedef float f32x4 __attribute__((ext_vector_type(4)));

#if __has_builtin(__builtin_amdgcn_fdot2)
#define FDOT2(a, b, c) __builtin_amdgcn_fdot2((a), (b), (c), false)
#else
static __device__ __forceinline__ float fdot2_fb(half2v a, half2v b, float c) {
    return c + (float)a[0] * (float)b[0] + (float)a[1] * (float)b[1];
}
#define FDOT2(a, b, c) fdot2_fb((a), (b), (c))
#endif

#define SV2(v, i0, i1) __builtin_shufflevector((v), (v), (i0), (i1))

__device__ __forceinline__ float sigm(float x) { return 1.0f / (1.0f + __expf(-x)); }
__device__ __forceinline__ float tanh_(float x) { return 1.0f - 2.0f / (__expf(2.0f * x) + 1.0f); }

// Problem constants
#define BB 128
#define TT 512
#define II 300
#define IIP 320   // padded K for fp16 path
#define HH 256
#define GG 1024  // 4*H

// ============================================================================
// Kernel 0: convert X (65536x300 f32) and W_ih_f (1024x300 f32) to fp16 with
// zero-padded K=320 rows, enabling 16B-aligned global_load_lds in the GEMM.
// ============================================================================
__global__ __launch_bounds__(256) void cvt_xw(
    const float* __restrict__ X, const float* __restrict__ W,
    _Float16* __restrict__ Xh, _Float16* __restrict__ Wh)
{
    const int total = (65536 + 1024) * 40;   // 8-elem chunks per padded row
    for (int c = blockIdx.x * 256 + threadIdx.x; c < total; c += gridDim.x * 256) {
        const int row = c / 40;
        const int ch = c - row * 40;
        const int k0 = ch * 8;
        const float* src;
        _Float16* dst;
        if (row < 65536) {
            src = X + (size_t)row * II;
            dst = Xh + (size_t)row * IIP;
        } else {
            src = W + (size_t)(row - 65536) * II;
            dst = Wh + (size_t)(row - 65536) * IIP;
        }
        half8v hv;
        if (k0 + 8 <= II) {
            float4 a = *(const float4*)(src + k0);
            float4 b = *(const float4*)(src + k0 + 4);
            hv = half8v{(_Float16)a.x, (_Float16)a.y, (_Float16)a.z, (_Float16)a.w,
                        (_Float16)b.x, (_Float16)b.y, (_Float16)b.z, (_Float16)b.w};
        } else {
#pragma unroll
            for (int q = 0; q < 8; ++q) {
                const int k = k0 + q;
                hv[q] = (k < II) ? (_Float16)src[k] : (_Float16)0.f;
            }
        }
        *(half8v*)(dst + k0) = hv;
    }
}

// ============================================================================
// Kernel 1b: xp GEMM, fp16 inputs via global_load_lds (m97 structure). PROVEN.
// ============================================================================
#if __has_builtin(__builtin_amdgcn_global_load_lds)
#define HAVE_GLL 1
__device__ __forceinline__ void gll16(const _Float16* g, _Float16* l) {
    __builtin_amdgcn_global_load_lds(
        (const __attribute__((address_space(1))) void*)g,
        (__attribute__((address_space(3))) void*)l, 16, 0, 0);
}
#else
#define HAVE_GLL 0
#endif

__global__ __launch_bounds__(256) void gemm_xp_h(
    const _Float16* __restrict__ Xh, const _Float16* __restrict__ Wh,
    const float* __restrict__ bias, _Float16* __restrict__ XP)
{
    __shared__ __align__(16) _Float16 As[128 * 32];
    __shared__ __align__(16) _Float16 Bs[128 * 32];

    const int t = threadIdx.x;
    const int m0 = blockIdx.y * 128;
    const int n0 = blockIdx.x * 128;
    const int lane = t & 63;
    const int wv = t >> 6;
    const int mq = (wv >> 1) * 4;
    const int nq = (wv & 1) * 4;

    int rowd[2], k4d[2], cidx[2];
#pragma unroll
    for (int r = 0; r < 2; ++r) {
        const int c = wv * 128 + r * 64 + lane;
        cidx[r] = c;
        rowd[r] = ((c >> 6) << 4) | (c & 15);
        k4d[r] = (c >> 4) & 3;
    }

    f32x4 acc[4][4];
#pragma unroll
    for (int i = 0; i < 4; ++i)
#pragma unroll
        for (int j = 0; j < 4; ++j) acc[i][j] = f32x4{0.f, 0.f, 0.f, 0.f};

    for (int kc = 0; kc < IIP; kc += 32) {
        __syncthreads();
#pragma unroll
        for (int r = 0; r < 2; ++r) {
            const _Float16* ga = Xh + (size_t)(m0 + rowd[r]) * IIP + kc + k4d[r] * 8;
            const _Float16* gb = Wh + (size_t)(n0 + rowd[r]) * IIP + kc + k4d[r] * 8;
#if HAVE_GLL
            gll16(ga, &As[cidx[r] * 8]);
            gll16(gb, &Bs[cidx[r] * 8]);
#else
            *(half8v*)(&As[cidx[r] * 8]) = *(const half8v*)ga;
            *(half8v*)(&Bs[cidx[r] * 8]) = *(const half8v*)gb;
#endif
        }
        __syncthreads();

        half8v af[4], bf[4];
#pragma unroll
        for (int i = 0; i < 4; ++i) {
            af[i] = *(const half8v*)(&As[(mq + i) * 512 + (lane >> 4) * 128 + (lane & 15) * 8]);
            bf[i] = *(const half8v*)(&Bs[(nq + i) * 512 + (lane >> 4) * 128 + (lane & 15) * 8]);
        }
#pragma unroll
        for (int i = 0; i < 4; ++i)
#pragma unroll
            for (int j = 0; j < 4; ++j)
                acc[i][j] = __builtin_amdgcn_mfma_f32_16x16x32_f16(af[i], bf[j], acc[i][j], 0, 0, 0);
    }

#pragma unroll
    for (int j = 0; j < 4; ++j) {
        const int n = n0 + (nq + j) * 16 + (lane & 15);
        const float bv = bias[n];
#pragma unroll
        for (int i = 0; i < 4; ++i) {
#pragma unroll
            for (int r = 0; r < 4; ++r) {
                const int m = m0 + (mq + i) * 16 + (lane >> 4) * 4 + r;
                XP[(size_t)m * GG + n] = (_Float16)(acc[i][j][r] + bv);
            }
        }
    }
}

// ============================================================================
// Kernel 1 (fallback): xp GEMM from f32 inputs (the proven v1 kernel).
// ============================================================================
__global__ __launch_bounds__(256, 3) void gemm_xp(
    const float* __restrict__ X, const float* __restrict__ W,
    const float* __restrict__ bias, _Float16* __restrict__ XP)
{
    __shared__ _Float16 As[128 * 32];
    __shared__ _Float16 Bs[128 * 32];

    const int t = threadIdx.x;
    const int m0 = blockIdx.y * 128;
    const int n0 = blockIdx.x * 128;
    const int kpos = t & 7;
    const int rbase = t >> 3;
    const int lane = t & 63;
    const int wv = t >> 6;
    const int mq = (wv >> 1) * 4;
    const int nq = (wv & 1) * 4;

    f32x4 acc[4][4];
#pragma unroll
    for (int i = 0; i < 4; ++i)
#pragma unroll
        for (int j = 0; j < 4; ++j) acc[i][j] = f32x4{0.f, 0.f, 0.f, 0.f};

    for (int kc = 0; kc < 320; kc += 32) {
        __syncthreads();
        const int k0 = kc + kpos * 4;
#pragma unroll
        for (int rr = 0; rr < 4; ++rr) {
            const int row = rbase + rr * 32;
            float4 va = {0.f, 0.f, 0.f, 0.f}, vb = {0.f, 0.f, 0.f, 0.f};
            if (k0 < 300) {
                va = *(const float4*)(X + (size_t)(m0 + row) * II + k0);
                vb = *(const float4*)(W + (size_t)(n0 + row) * II + k0);
            }
            const int idx = (row >> 4) * 512 + (kpos >> 1) * 128 + (row & 15) * 8 + (kpos & 1) * 4;
            half4v ha = {(_Float16)va.x, (_Float16)va.y, (_Float16)va.z, (_Float16)va.w};
            half4v hb = {(_Float16)vb.x, (_Float16)vb.y, (_Float16)vb.z, (_Float16)vb.w};
            *(half4v*)(&As[idx]) = ha;
            *(half4v*)(&Bs[idx]) = hb;
        }
        __syncthreads();

        half8v af[4], bf[4];
#pragma unroll
        for (int i = 0; i < 4; ++i) {
            af[i] = *(const half8v*)(&As[(mq + i) * 512 + (lane >> 4) * 128 + (lane & 15) * 8]);
            bf[i] = *(const half8v*)(&Bs[(nq + i) * 512 + (lane >> 4) * 128 + (lane & 15) * 8]);
        }
#pragma unroll
        for (int i = 0; i < 4; ++i)
#pragma unroll
            for (int j = 0; j < 4; ++j)
                acc[i][j] = __builtin_amdgcn_mfma_f32_16x16x32_f16(af[i], bf[j], acc[i][j], 0, 0, 0);
    }

#pragma unroll
    for (int j = 0; j < 4; ++j) {
        const int n = n0 + (nq + j) * 16 + (lane & 15);
        const float bv = bias[n];
#pragma unroll
        for (int i = 0; i < 4; ++i) {
#pragma unroll
            for (int r = 0; r < 4; ++r) {
                const int m = m0 + (mq + i) * 16 + (lane >> 4) * 4 + r;
                XP[(size_t)m * GG + n] = (_Float16)(acc[i][j][r] + bv);
            }
        }
    }
}

// ============================================================================
// Kernel 2 (v8): v1 verbatim + split accumulators (4 FDOT2 chains/thread).
//
// Storage-wall lesson (v5/v6/v7b): weights occupy 521 KB of the 672 KB
// on-CU storage; headroom < ~4 regs, so every ILP scheme that adds state
// spills. v8 is the one register-NEUTRAL lever: split each 128-deep FDOT2
// chain into lo/hi halves (a0L/a0H, a1L/a1H: 4 chains/thread, 8/SIMD),
// funded by dropping the cross-step xp prefetch (x loaded at step top,
// ~3000 cyc of cover to its use at step end; frees the nx pair + pointer).
// Everything else — w0/w1 residency, wlds, row mapping, shfl_xor(32)
// exchange, ONE barrier/step — is v1 verbatim.
// ============================================================================
__global__ __attribute__((amdgpu_flat_work_group_size(512, 512), amdgpu_waves_per_eu(2, 2)))
void lstm_fwd(
    const float* __restrict__ Whh, const _Float16* __restrict__ XP,
    float* __restrict__ HF)
{
    __shared__ _Float16 wlds[8 * GG * 8];            // 128 KB: [grp][row][8]
    __shared__ __align__(16) _Float16 hlds[2][HH];   // 1 KB ping-pong

    const int t = threadIdx.x;
    const int b = blockIdx.x;
    const int l = t & 63;
    const int wv = t >> 6;
    const int half = l >> 5;               // 0: (i,g) rows, 1: (f,o) rows
    const int j = wv * 32 + (l & 31);      // gate index 0..255
    const int row0 = j + (half ? 256 : 0); // i_j or f_j
    const int row1 = row0 + 512;           // g_j or o_j

    // ---- resident weights: k = 0..191 for both owned rows (192 VGPRs) ----
    half2v w0[96], w1[96];
#pragma unroll
    for (int i = 0; i < 48; ++i) {
        float4 v = *(const float4*)(Whh + (size_t)row0 * HH + i * 4);
        w0[2 * i]     = half2v{(_Float16)v.x, (_Float16)v.y};
        w0[2 * i + 1] = half2v{(_Float16)v.z, (_Float16)v.w};
    }
#pragma unroll
    for (int i = 0; i < 48; ++i) {
        float4 v = *(const float4*)(Whh + (size_t)row1 * HH + i * 4);
        w1[2 * i]     = half2v{(_Float16)v.x, (_Float16)v.y};
        w1[2 * i + 1] = half2v{(_Float16)v.z, (_Float16)v.w};
    }
    // ---- LDS weights: k = 192..255, filled by row index t and t+512 ----
#pragma unroll
    for (int grp = 0; grp < 8; ++grp) {
        float4 a  = *(const float4*)(Whh + (size_t)t * HH + 192 + grp * 8);
        float4 c4 = *(const float4*)(Whh + (size_t)t * HH + 192 + grp * 8 + 4);
        half8v hv = {(_Float16)a.x, (_Float16)a.y, (_Float16)a.z, (_Float16)a.w,
                     (_Float16)c4.x, (_Float16)c4.y, (_Float16)c4.z, (_Float16)c4.w};
        *(half8v*)(&wlds[grp * (GG * 8) + t * 8]) = hv;
        float4 a2 = *(const float4*)(Whh + (size_t)(t + 512) * HH + 192 + grp * 8);
        float4 c2 = *(const float4*)(Whh + (size_t)(t + 512) * HH + 192 + grp * 8 + 4);
        half8v hv2 = {(_Float16)a2.x, (_Float16)a2.y, (_Float16)a2.z, (_Float16)a2.w,
                      (_Float16)c2.x, (_Float16)c2.y, (_Float16)c2.z, (_Float16)c2.w};
        *(half8v*)(&wlds[grp * (GG * 8) + (t + 512) * 8]) = hv2;
    }
    if (t < HH) hlds[0][t] = (_Float16)0.f;
    float c = 0.0f;
    __syncthreads();

    for (int ts = 0; ts < TT; ++ts) {
        const int p = ts & 1;
        const _Float16* hrd = &hlds[p][0];
        // x for THIS step, issued at step top (used ~full step later)
        const _Float16* xrow = XP + ((size_t)b * TT + ts) * GG;
        const _Float16 x0 = xrow[row0];
        const _Float16 x1 = xrow[row1];

        float a0L = 0.f, a1L = 0.f, a0H = 0.f, a1H = 0.f;
#pragma unroll
        for (int cq = 0; cq < 12; ++cq) {  // k = 0..95 -> lo chains
            half8v hv = *(const half8v*)(&hrd[cq * 8]);
            a0L = FDOT2(SV2(hv, 0, 1), w0[cq * 4 + 0], a0L);
            a1L = FDOT2(SV2(hv, 0, 1), w1[cq * 4 + 0], a1L);
            a0L = FDOT2(SV2(hv, 2, 3), w0[cq * 4 + 1], a0L);
            a1L = FDOT2(SV2(hv, 2, 3), w1[cq * 4 + 1], a1L);
            a0L = FDOT2(SV2(hv, 4, 5), w0[cq * 4 + 2], a0L);
            a1L = FDOT2(SV2(hv, 4, 5), w1[cq * 4 + 2], a1L);
            a0L = FDOT2(SV2(hv, 6, 7), w0[cq * 4 + 3], a0L);
            a1L = FDOT2(SV2(hv, 6, 7), w1[cq * 4 + 3], a1L);
        }
#pragma unroll
        for (int cq = 12; cq < 24; ++cq) {  // k = 96..191 -> hi chains
            half8v hv = *(const half8v*)(&hrd[cq * 8]);
            a0H = FDOT2(SV2(hv, 0, 1), w0[cq * 4 + 0], a0H);
            a1H = FDOT2(SV2(hv, 0, 1), w1[cq * 4 + 0], a1H);
            a0H = FDOT2(SV2(hv, 2, 3), w0[cq * 4 + 1], a0H);
            a1H = FDOT2(SV2(hv, 2, 3), w1[cq * 4 + 1], a1H);
            a0H = FDOT2(SV2(hv, 4, 5), w0[cq * 4 + 2], a0H);
            a1H = FDOT2(SV2(hv, 4, 5), w1[cq * 4 + 2], a1H);
            a0H = FDOT2(SV2(hv, 6, 7), w0[cq * 4 + 3], a0H);
            a1H = FDOT2(SV2(hv, 6, 7), w1[cq * 4 + 3], a1H);
        }
#define LDS_W_STEP(ACC0, ACC1, I0, I1)                                     \
        {                                                                  \
            half2v hp  = SV2(hv, I0, I1);                                  \
            half2v wap = SV2(wa, I0, I1);                                  \
            half2v wbp = SV2(wb, I0, I1);                                  \
            ACC0 = FDOT2(hp, wap, ACC0);                                   \
            ACC1 = FDOT2(hp, wbp, ACC1);                                   \
        }
#pragma unroll
        for (int grp = 0; grp < 8; ++grp) {  // k = 192..255 from LDS weights
            half8v hv = *(const half8v*)(&hrd[192 + grp * 8]);
            half8v wa = *(const half8v*)(&wlds[grp * (GG * 8) + row0 * 8]);
            half8v wb = *(const half8v*)(&wlds[grp * (GG * 8) + row1 * 8]);
            if (grp & 1) {
                LDS_W_STEP(a0H, a1H, 0, 1)
                LDS_W_STEP(a0H, a1H, 2, 3)
                LDS_W_STEP(a0H, a1H, 4, 5)
                LDS_W_STEP(a0H, a1H, 6, 7)
            } else {
                LDS_W_STEP(a0L, a1L, 0, 1)
                LDS_W_STEP(a0L, a1L, 2, 3)
                LDS_W_STEP(a0L, a1L, 4, 5)
                LDS_W_STEP(a0L, a1L, 6, 7)
            }
        }
#undef LDS_W_STEP
        const float o0 = (a0L + a0H) + (float)x0;
        const float o1 = (a1L + a1H) + (float)x1;
        // partner exchange within the wave (lanes l <-> l^32)
        const float p0 = __shfl_xor(o0, 32, 64);
        const float p1 = __shfl_xor(o1, 32, 64);
        const float gi = half ? p0 : o0;
        const float gg = half ? p1 : o1;
        const float gf = half ? o0 : p0;
        const float go = half ? o1 : p1;
        c = sigm(gf) * c + sigm(gi) * tanh_(gg);
        const float h = sigm(go) * tanh_(c);
        if (!half) {
            hlds[p ^ 1][j] = (_Float16)h;
            if (ts == TT - 1) HF[(size_t)b * HH + j] = h;
        }
        __syncthreads();
    }
}

// ============================================================================
// Kernel 3: backward direction = ONE cell step on x[:, T-1] with h0=c0=0.
// ============================================================================
__global__ __launch_bounds__(256) void lstm_bwd(
    const float* __restrict__ X, const float* __restrict__ Wih,
    const float* __restrict__ bb, float* __restrict__ HB)
{
    __shared__ float xs[II];
    const int b = blockIdx.x, t = threadIdx.x;
    const float* xrow = X + ((size_t)b * TT + (TT - 1)) * II;
    if (t < 75) *(float4*)(&xs[t * 4]) = *(const float4*)(xrow + t * 4);
    __syncthreads();
    if (t < HH) {
        float ai = 0.f, ag = 0.f, ao = 0.f;
        const float4* wi = (const float4*)(Wih + (size_t)t * II);
        const float4* wg = (const float4*)(Wih + (size_t)(t + 512) * II);
        const float4* wo = (const float4*)(Wih + (size_t)(t + 768) * II);
        for (int k4 = 0; k4 < 75; ++k4) {
            float4 xv = *(const float4*)(&xs[k4 * 4]);
            float4 a = wi[k4], g4 = wg[k4], o4 = wo[k4];
            ai += xv.x * a.x + xv.y * a.y + xv.z * a.z + xv.w * a.w;
            ag += xv.x * g4.x + xv.y * g4.y + xv.z * g4.z + xv.w * g4.w;
            ao += xv.x * o4.x + xv.y * o4.y + xv.z * o4.z + xv.w * o4.w;
        }
        ai += bb[t];
        ag += bb[t + 512];
        ao += bb[t + 768];
        const float cg = sigm(ai) * tanh_(ag);
        HB[(size_t)b * HH + t] = sigm(ao) * tanh_(cg);
    }
}

// ============================================================================
// Kernel 4: out[b][jj] = [hf|hb] . W_lin[jj] + b_lin[jj]
// ============================================================================
__global__ __launch_bounds__(256) void final_k(
    const float* __restrict__ HF, const float* __restrict__ HB,
    const float* __restrict__ Wlin, const float* __restrict__ blin,
    float* __restrict__ OUT)
{
    const int t = threadIdx.x;
    const int b = t >> 1, jj = t & 1;
    float acc = blin[jj];
    const float* wf = Wlin + jj * 512;
    const float* wb = Wlin + jj * 512 + 256;
    const float* hf = HF + (size_t)b * HH;
    const float* hb = HB + (size_t)b * HH;
    for (int k = 0; k < HH; k += 4) {
        float4 h4 = *(const float4*)(hf + k);
        float4 w4 = *(const float4*)(wf + k);
        float4 g4 = *(const float4*)(hb + k);
        float4 v4 = *(const float4*)(wb + k);
        acc += h4.x * w4.x + h4.y * w4.y + h4.z * w4.z + h4.w * w4.w;
        acc += g4.x * v4.x + g4.y * v4.y + g4.z * v4.z + g4.w * v4.w;
    }
    OUT[b * 2 + jj] = acc;
}

// ============================================================================
extern "C" void kernel_launch(void* const* d_in, const int* in_sizes, int n_in,
                              void* d_out, int out_size, void* d_ws, size_t ws_size,
                              hipStream_t stream)
{
    const float* x = (const float*)d_in[0];
    const float* Wihf = (const float*)d_in[1];
    const float* Whhf = (const float*)d_in[2];
    const float* bf = (const float*)d_in[3];
    const float* Wihb = (const float*)d_in[4];
    const float* Whhb = (const float*)d_in[5];
    const float* bbv = (const float*)d_in[6];
    const float* Wlin = (const float*)d_in[7];
    const float* blin = (const float*)d_in[8];
    float* out = (float*)d_out;
    (void)Whhb; (void)in_sizes; (void)n_in; (void)out_size;

    // workspace layout: xp fp16 | hf f32 | hb f32 | Xh fp16 | Wh fp16
    const size_t XP_B = (size_t)BB * TT * GG * 2;            // 134,217,728
    const size_t H_B  = (size_t)BB * HH * 4;                 // 131,072
    const size_t XH_B = (size_t)65536 * IIP * 2;             // 41,943,040
    const size_t WH_B = (size_t)GG * IIP * 2;                // 655,360

    _Float16* xp = (_Float16*)d_ws;
    float* hf = (float*)((char*)d_ws + XP_B);
    float* hb = hf + (size_t)BB * HH;
    _Float16* Xh = (_Float16*)((char*)d_ws + XP_B + 2 * H_B);
    _Float16* Wh = Xh + (size_t)65536 * IIP;

    lstm_bwd<<<BB, 256, 0, stream>>>(x, Wihb, bbv, hb);
    if (ws_size >= XP_B + 2 * H_B + XH_B + WH_B) {
        cvt_xw<<<2048, 256, 0, stream>>>(x, Wihf, Xh, Wh);
        gemm_xp_h<<<dim3(GG / 128, (BB * TT) / 128), 256, 0, stream>>>(Xh, Wh, bf, xp);
    } else {
        gemm_xp<<<dim3(GG / 128, (BB * TT) / 128), 256, 0, stream>>>(x, Wihf, bf, xp);
    }
    lstm_fwd<<<BB, 512, 0, stream>>>(Whhf, xp, hf);
    final_k<<<1, 256, 0, stream>>>(hf, hb, Wlin, blin, out);
}